// Round 1
// baseline (579.642 us; speedup 1.0000x reference)
//
#include <hip/hip_runtime.h>
#include <math.h>
#include <stdint.h>

#define TOKENS 8192
#define DIM 1024
#define N3 3072
#define NSEQ 2048
#define NH 16
#define DH 64

typedef __attribute__((ext_vector_type(8))) __bf16 bf16x8;
typedef __attribute__((ext_vector_type(4))) float f32x4;
typedef __attribute__((ext_vector_type(4))) short short4v;

__device__ inline unsigned short f2bf(float f) {
    union { float f; unsigned u; } c; c.f = f;
    unsigned u = c.u + 0x7fffu + ((c.u >> 16) & 1u);
    return (unsigned short)(u >> 16);
}

__device__ __forceinline__ void glds16(const void* g, void* l) {
    __builtin_amdgcn_global_load_lds((__attribute__((address_space(1))) void*)(void*)g,
                                     (__attribute__((address_space(3))) void*)l, 16, 0, 0);
}

// ---------------- transpose f32 [R][C] -> bf16 [C][R] ----------------
__global__ __launch_bounds__(256) void transpose_to_bf16(
    const float* __restrict__ in, unsigned short* __restrict__ out, int R, int C) {
    __shared__ float tile[64][65];
    int n0 = blockIdx.x * 64, k0 = blockIdx.y * 64;
    int t = threadIdx.x;
#pragma unroll
    for (int i = 0; i < 16; i++) {
        int idx = i * 256 + t;
        int r = idx >> 6, c = idx & 63;
        tile[r][c] = in[(size_t)(k0 + r) * C + n0 + c];
    }
    __syncthreads();
#pragma unroll
    for (int i = 0; i < 16; i++) {
        int idx = i * 256 + t;
        int r = idx >> 6, c = idx & 63;
        out[(size_t)(n0 + r) * R + k0 + c] = f2bf(tile[c][r]);
    }
}

// ---------------- LayerNorm: f32 [8192][1024] -> bf16 ----------------
__global__ __launch_bounds__(256) void ln_kernel(
    const float* __restrict__ x, const float* __restrict__ gamma,
    const float* __restrict__ beta, unsigned short* __restrict__ xn) {
    int row = blockIdx.x;
    int t = threadIdx.x;
    const float4 v = ((const float4*)(x + (size_t)row * DIM))[t];
    float s = v.x + v.y + v.z + v.w;
    float sq = v.x * v.x + v.y * v.y + v.z * v.z + v.w * v.w;
#pragma unroll
    for (int m = 1; m < 64; m <<= 1) {
        s += __shfl_xor(s, m);
        sq += __shfl_xor(sq, m);
    }
    __shared__ float ws[4], wq[4];
    int w = t >> 6, lane = t & 63;
    if (lane == 0) { ws[w] = s; wq[w] = sq; }
    __syncthreads();
    s = ws[0] + ws[1] + ws[2] + ws[3];
    sq = wq[0] + wq[1] + wq[2] + wq[3];
    float mu = s * (1.0f / DIM);
    float var = sq * (1.0f / DIM) - mu * mu;
    float rstd = rsqrtf(var + 1e-5f);
    const float4 g = ((const float4*)gamma)[t];
    const float4 bb = ((const float4*)beta)[t];
    short4v o;
    o[0] = (short)f2bf((v.x - mu) * rstd * g.x + bb.x);
    o[1] = (short)f2bf((v.y - mu) * rstd * g.y + bb.y);
    o[2] = (short)f2bf((v.z - mu) * rstd * g.z + bb.z);
    o[3] = (short)f2bf((v.w - mu) * rstd * g.w + bb.w);
    *(short4v*)(xn + (size_t)row * DIM + t * 4) = o;
}

// ---------------- shared GEMM core: C[128x128] = A[M,K] * Bt[N,K]^T ----------------
__device__ __forceinline__ void gemm_core(
    const unsigned short* __restrict__ A, const unsigned short* __restrict__ Bt, int K,
    int brow, int bcol, short* As, short* Bs, f32x4 acc[4][4]) {
    int t = threadIdx.x, w = t >> 6, lane = t & 63;
    int wr = w >> 1, wc = w & 1;
    int srow = lane >> 2, scol = (lane & 3) * 8;
    for (int k0 = 0; k0 < K; k0 += 32) {
        __syncthreads();
#pragma unroll
        for (int i = 0; i < 2; i++) {
            int c = i * 4 + w;
            glds16(A + (size_t)(brow + 16 * c + srow) * K + k0 + scol, (char*)As + c * 1024);
            glds16(Bt + (size_t)(bcol + 16 * c + srow) * K + k0 + scol, (char*)Bs + c * 1024);
        }
        __syncthreads();
        bf16x8 a[4], b[4];
#pragma unroll
        for (int i = 0; i < 4; i++) {
            a[i] = *(const bf16x8*)&As[(wr * 64 + i * 16 + (lane & 15)) * 32 + (lane >> 4) * 8];
            b[i] = *(const bf16x8*)&Bs[(wc * 64 + i * 16 + (lane & 15)) * 32 + (lane >> 4) * 8];
        }
#pragma unroll
        for (int i = 0; i < 4; i++)
#pragma unroll
            for (int j = 0; j < 4; j++)
                acc[i][j] = __builtin_amdgcn_mfma_f32_16x16x32_bf16(a[i], b[j], acc[i][j], 0, 0, 0);
    }
}

// QKV GEMM: xn[8192][1024] @ w_qkv -> writes Q (scaled), K, V^T in [b,h,...] layouts
#define QSCALE_LOG2E 0.18033688011112042f  // (1/sqrt(64)) * log2(e)

__global__ __launch_bounds__(256) void gemm_qkv(
    const unsigned short* __restrict__ A, const unsigned short* __restrict__ Bt,
    unsigned short* __restrict__ Qb, unsigned short* __restrict__ Kb,
    unsigned short* __restrict__ Vt) {
    __shared__ __align__(16) short As[128 * 32];
    __shared__ __align__(16) short Bs[128 * 32];
    int brow = blockIdx.y * 128, bcol = blockIdx.x * 128;
    f32x4 acc[4][4] = {};
    gemm_core(A, Bt, DIM, brow, bcol, As, Bs, acc);

    int t = threadIdx.x, w = t >> 6, lane = t & 63;
    int wr = w >> 1, wc = w & 1;
    int part = bcol >> 10;  // uniform per block: 0=q 1=k 2=v
#pragma unroll
    for (int i = 0; i < 4; i++) {
#pragma unroll
        for (int j = 0; j < 4; j++) {
            int col = bcol + wc * 64 + j * 16 + (lane & 15);
            int within = col & 1023;
            int h = within >> 6, d = within & 63;
            int rowb = brow + wr * 64 + i * 16 + (lane >> 4) * 4;
            if (part == 2) {
                // V^T: n consecutive over r -> pack 4
                int b = rowb >> 11, n = rowb & 2047;
                int bh = (b << 4) + h;
                short4v pv;
#pragma unroll
                for (int r = 0; r < 4; r++) pv[r] = (short)f2bf(acc[i][j][r]);
                *(short4v*)(Vt + ((size_t)bh * 64 + d) * 2048 + n) = pv;
            } else {
#pragma unroll
                for (int r = 0; r < 4; r++) {
                    int row = rowb + r;
                    int b = row >> 11, n = row & 2047;
                    int bh = (b << 4) + h;
                    float val = acc[i][j][r];
                    if (part == 0)
                        Qb[((size_t)bh * 2048 + n) * 64 + d] = f2bf(val * QSCALE_LOG2E);
                    else
                        Kb[((size_t)bh * 2048 + n) * 64 + d] = f2bf(val);
                }
            }
        }
    }
}

// out GEMM: att[8192][1024] @ w_out + b_out -> f32 out
__global__ __launch_bounds__(256) void gemm_out(
    const unsigned short* __restrict__ A, const unsigned short* __restrict__ Bt,
    const float* __restrict__ bias, float* __restrict__ out) {
    __shared__ __align__(16) short As[128 * 32];
    __shared__ __align__(16) short Bs[128 * 32];
    int brow = blockIdx.y * 128, bcol = blockIdx.x * 128;
    f32x4 acc[4][4] = {};
    gemm_core(A, Bt, DIM, brow, bcol, As, Bs, acc);

    int t = threadIdx.x, w = t >> 6, lane = t & 63;
    int wr = w >> 1, wc = w & 1;
#pragma unroll
    for (int i = 0; i < 4; i++) {
#pragma unroll
        for (int j = 0; j < 4; j++) {
            int col = bcol + wc * 64 + j * 16 + (lane & 15);
            float bv = bias[col];
#pragma unroll
            for (int r = 0; r < 4; r++) {
                int row = brow + wr * 64 + i * 16 + (lane >> 4) * 4 + r;
                out[(size_t)row * DIM + col] = acc[i][j][r] + bv;
            }
        }
    }
}

// ---------------- flash attention ----------------
// grid (NSEQ/64, 64): x = q-tile, y = b*16+h. 4 waves * 16 q-rows each. KV tile 64.
__global__ __launch_bounds__(256) void attn_kernel(
    const unsigned short* __restrict__ Qb, const unsigned short* __restrict__ Kb,
    const unsigned short* __restrict__ Vt, const float* __restrict__ pos,
    unsigned short* __restrict__ att) {
    __shared__ __align__(16) char Plds[4 * 2048];
    int t = threadIdx.x, w = t >> 6, lane = t & 63;
    int q16 = lane & 15, g = lane >> 4;
    int bh = blockIdx.y;
    int b = bh >> 4, h = bh & 15;
    int qrow = blockIdx.x * 64 + w * 16 + q16;  // this lane's q row

    const unsigned short* Qh = Qb + (size_t)bh * NSEQ * DH;
    const unsigned short* Kh = Kb + (size_t)bh * NSEQ * DH;
    const unsigned short* Vh = Vt + (size_t)bh * DH * NSEQ;

    bf16x8 qf[2];
#pragma unroll
    for (int ks = 0; ks < 2; ks++)
        qf[ks] = *(const bf16x8*)(Qh + (size_t)qrow * DH + ks * 32 + g * 8);

    f32x4 accT[4] = {};
    float mrun = -INFINITY, lsum = 0.f;
    char* Pw = Plds + w * 2048 + q16 * 128;
    int swz = (q16 & 7) << 4;

    for (int kv0 = 0; kv0 < NSEQ; kv0 += 64) {
        // S^T tile: st[mf] holds kv rows (kv0 + mf*16 + g*4 + r), col = q16
        f32x4 st[4];
#pragma unroll
        for (int mf = 0; mf < 4; mf++) {
            f32x4 s = {0.f, 0.f, 0.f, 0.f};
#pragma unroll
            for (int ks = 0; ks < 2; ks++) {
                bf16x8 kf = *(const bf16x8*)(Kh + (size_t)(kv0 + mf * 16 + q16) * DH + ks * 32 + g * 8);
                s = __builtin_amdgcn_mfma_f32_16x16x32_bf16(kf, qf[ks], s, 0, 0, 0);
            }
            st[mf] = s;
        }
        // online softmax (log2 domain; scale folded into Q)
        float pm = st[0][0];
#pragma unroll
        for (int mf = 0; mf < 4; mf++)
#pragma unroll
            for (int r = 0; r < 4; r++) pm = fmaxf(pm, st[mf][r]);
        pm = fmaxf(pm, __shfl_xor(pm, 16));
        pm = fmaxf(pm, __shfl_xor(pm, 32));
        float mnew = fmaxf(mrun, pm);
        float scale = exp2f(mrun - mnew);
        float p[4][4];
        float rsum = 0.f;
#pragma unroll
        for (int mf = 0; mf < 4; mf++)
#pragma unroll
            for (int r = 0; r < 4; r++) {
                float e = exp2f(st[mf][r] - mnew);
                p[mf][r] = e;
                rsum += e;
            }
        rsum += __shfl_xor(rsum, 16);
        rsum += __shfl_xor(rsum, 32);
        lsum = lsum * scale + rsum;
#pragma unroll
        for (int mf = 0; mf < 4; mf++) accT[mf] *= scale;
        mrun = mnew;

        // P -> LDS (bf16, XOR-swizzled), layout [q16][kv]
#pragma unroll
        for (int f = 0; f < 4; f++) {
            short4v pv;
#pragma unroll
            for (int r = 0; r < 4; r++) pv[r] = (short)f2bf(p[f][r]);
            *(short4v*)(Pw + ((f * 32 + g * 8) ^ swz)) = pv;
        }
        // PV: accT[mf] (d rows) += V^T * P^T
#pragma unroll
        for (int ks = 0; ks < 2; ks++) {
            bf16x8 pb = *(const bf16x8*)(Pw + ((ks * 64 + g * 16) ^ swz));
#pragma unroll
            for (int mf = 0; mf < 4; mf++) {
                bf16x8 vf = *(const bf16x8*)(Vh + (size_t)(mf * 16 + q16) * NSEQ + kv0 + ks * 32 + g * 8);
                accT[mf] = __builtin_amdgcn_mfma_f32_16x16x32_bf16(vf, pb, accT[mf], 0, 0, 0);
            }
        }
    }

    // epilogue: out[q][d] = accT[d][q]/lsum + pos ; store bf16
    float inv = 1.0f / lsum;
    size_t rowbase = ((size_t)b * NSEQ + qrow) * DIM + h * 64;
#pragma unroll
    for (int mf = 0; mf < 4; mf++) {
        int dbase = mf * 16 + g * 4;
        float4 pv4 = *(const float4*)(pos + rowbase + dbase);
        short4v o;
        o[0] = (short)f2bf(accT[mf][0] * inv + pv4.x);
        o[1] = (short)f2bf(accT[mf][1] * inv + pv4.y);
        o[2] = (short)f2bf(accT[mf][2] * inv + pv4.z);
        o[3] = (short)f2bf(accT[mf][3] * inv + pv4.w);
        *(short4v*)(att + rowbase + dbase) = o;
    }
}

extern "C" void kernel_launch(void* const* d_in, const int* in_sizes, int n_in,
                              void* d_out, int out_size, void* d_ws, size_t ws_size,
                              hipStream_t stream) {
    const float* x = (const float*)d_in[0];
    const float* pos = (const float*)d_in[1];
    const float* w_qkv = (const float*)d_in[2];
    const float* w_out = (const float*)d_in[3];
    const float* b_out = (const float*)d_in[4];
    const float* ln_g = (const float*)d_in[5];
    const float* ln_b = (const float*)d_in[6];
    float* out = (float*)d_out;

    char* ws = (char*)d_ws;
    unsigned short* xn      = (unsigned short*)(ws);                       // 16MB (reused as att)
    unsigned short* wqkv_bt = (unsigned short*)(ws + (16ull << 20));       // 6MB
    unsigned short* wout_bt = (unsigned short*)(ws + (22ull << 20));       // 2MB
    unsigned short* Qb      = (unsigned short*)(ws + (24ull << 20));       // 16MB
    unsigned short* Kb      = (unsigned short*)(ws + (40ull << 20));       // 16MB
    unsigned short* Vt      = (unsigned short*)(ws + (56ull << 20));       // 16MB
    unsigned short* att     = xn;                                          // reuse

    transpose_to_bf16<<<dim3(N3 / 64, DIM / 64), 256, 0, stream>>>(w_qkv, wqkv_bt, DIM, N3);
    transpose_to_bf16<<<dim3(DIM / 64, DIM / 64), 256, 0, stream>>>(w_out, wout_bt, DIM, DIM);
    ln_kernel<<<TOKENS, 256, 0, stream>>>(x, ln_g, ln_b, xn);
    gemm_qkv<<<dim3(N3 / 128, TOKENS / 128), 256, 0, stream>>>(xn, wqkv_bt, Qb, Kb, Vt);
    attn_kernel<<<dim3(NSEQ / 64, 64), 256, 0, stream>>>(Qb, Kb, Vt, pos, att);
    gemm_out<<<dim3(DIM / 128, TOKENS / 128), 256, 0, stream>>>(att, wout_bt, b_out, out);
}

// Round 2
// 276.203 us; speedup vs baseline: 2.0986x; 2.0986x over previous
//
#include <hip/hip_runtime.h>
#include <math.h>
#include <stdint.h>

#define TOKENS 8192
#define DIM 1024
#define N3 3072
#define NSEQ 2048
#define NH 16
#define DH 64

typedef __attribute__((ext_vector_type(8))) __bf16 bf16x8;
typedef __attribute__((ext_vector_type(4))) float f32x4;
typedef __attribute__((ext_vector_type(4))) short short4v;

__device__ inline unsigned short f2bf(float f) {
    union { float f; unsigned u; } c; c.f = f;
    unsigned u = c.u + 0x7fffu + ((c.u >> 16) & 1u);
    return (unsigned short)(u >> 16);
}

__device__ __forceinline__ void glds16(const void* g, void* l) {
    __builtin_amdgcn_global_load_lds((__attribute__((address_space(1))) void*)(void*)g,
                                     (__attribute__((address_space(3))) void*)l, 16, 0, 0);
}

// ---------------- transpose f32 [R][C] -> bf16 [C][R] ----------------
__global__ __launch_bounds__(256) void transpose_to_bf16(
    const float* __restrict__ in, unsigned short* __restrict__ out, int R, int C) {
    __shared__ float tile[64][65];
    int n0 = blockIdx.x * 64, k0 = blockIdx.y * 64;
    int t = threadIdx.x;
#pragma unroll
    for (int i = 0; i < 16; i++) {
        int idx = i * 256 + t;
        int r = idx >> 6, c = idx & 63;
        tile[r][c] = in[(size_t)(k0 + r) * C + n0 + c];
    }
    __syncthreads();
#pragma unroll
    for (int i = 0; i < 16; i++) {
        int idx = i * 256 + t;
        int r = idx >> 6, c = idx & 63;
        out[(size_t)(n0 + r) * R + k0 + c] = f2bf(tile[c][r]);
    }
}

// ---------------- LayerNorm: f32 [8192][1024] -> bf16 ----------------
__global__ __launch_bounds__(256) void ln_kernel(
    const float* __restrict__ x, const float* __restrict__ gamma,
    const float* __restrict__ beta, unsigned short* __restrict__ xn) {
    int row = blockIdx.x;
    int t = threadIdx.x;
    const float4 v = ((const float4*)(x + (size_t)row * DIM))[t];
    float s = v.x + v.y + v.z + v.w;
    float sq = v.x * v.x + v.y * v.y + v.z * v.z + v.w * v.w;
#pragma unroll
    for (int m = 1; m < 64; m <<= 1) {
        s += __shfl_xor(s, m);
        sq += __shfl_xor(sq, m);
    }
    __shared__ float ws[4], wq[4];
    int w = t >> 6, lane = t & 63;
    if (lane == 0) { ws[w] = s; wq[w] = sq; }
    __syncthreads();
    s = ws[0] + ws[1] + ws[2] + ws[3];
    sq = wq[0] + wq[1] + wq[2] + wq[3];
    float mu = s * (1.0f / DIM);
    float var = sq * (1.0f / DIM) - mu * mu;
    float rstd = rsqrtf(var + 1e-5f);
    const float4 g = ((const float4*)gamma)[t];
    const float4 bb = ((const float4*)beta)[t];
    short4v o;
    o[0] = (short)f2bf((v.x - mu) * rstd * g.x + bb.x);
    o[1] = (short)f2bf((v.y - mu) * rstd * g.y + bb.y);
    o[2] = (short)f2bf((v.z - mu) * rstd * g.z + bb.z);
    o[3] = (short)f2bf((v.w - mu) * rstd * g.w + bb.w);
    *(short4v*)(xn + (size_t)row * DIM + t * 4) = o;
}

// ---------------- shared GEMM core: C[128x128] = A[M,K] * Bt[N,K]^T ----------------
__device__ __forceinline__ void gemm_core(
    const unsigned short* __restrict__ A, const unsigned short* __restrict__ Bt, int K,
    int brow, int bcol, short* As, short* Bs, f32x4 acc[4][4]) {
    int t = threadIdx.x, w = t >> 6, lane = t & 63;
    int wr = w >> 1, wc = w & 1;
    int srow = lane >> 2, scol = (lane & 3) * 8;
    for (int k0 = 0; k0 < K; k0 += 32) {
        __syncthreads();
#pragma unroll
        for (int i = 0; i < 2; i++) {
            int c = i * 4 + w;
            glds16(A + (size_t)(brow + 16 * c + srow) * K + k0 + scol, (char*)As + c * 1024);
            glds16(Bt + (size_t)(bcol + 16 * c + srow) * K + k0 + scol, (char*)Bs + c * 1024);
        }
        __syncthreads();
        bf16x8 a[4], b[4];
#pragma unroll
        for (int i = 0; i < 4; i++) {
            a[i] = *(const bf16x8*)&As[(wr * 64 + i * 16 + (lane & 15)) * 32 + (lane >> 4) * 8];
            b[i] = *(const bf16x8*)&Bs[(wc * 64 + i * 16 + (lane & 15)) * 32 + (lane >> 4) * 8];
        }
#pragma unroll
        for (int i = 0; i < 4; i++)
#pragma unroll
            for (int j = 0; j < 4; j++)
                acc[i][j] = __builtin_amdgcn_mfma_f32_16x16x32_bf16(a[i], b[j], acc[i][j], 0, 0, 0);
    }
}

// QKV GEMM: xn[8192][1024] @ w_qkv -> writes Q (scaled), K, V^T in [b,h,...] layouts
#define QSCALE_LOG2E 0.18033688011112042f  // (1/sqrt(64)) * log2(e)

__global__ __launch_bounds__(256) void gemm_qkv(
    const unsigned short* __restrict__ A, const unsigned short* __restrict__ Bt,
    unsigned short* __restrict__ Qb, unsigned short* __restrict__ Kb,
    unsigned short* __restrict__ Vt) {
    __shared__ __align__(16) short As[128 * 32];
    __shared__ __align__(16) short Bs[128 * 32];
    int brow = blockIdx.y * 128, bcol = blockIdx.x * 128;
    f32x4 acc[4][4] = {};
    gemm_core(A, Bt, DIM, brow, bcol, As, Bs, acc);

    int t = threadIdx.x, w = t >> 6, lane = t & 63;
    int wr = w >> 1, wc = w & 1;
    int part = bcol >> 10;  // uniform per block: 0=q 1=k 2=v
#pragma unroll
    for (int i = 0; i < 4; i++) {
#pragma unroll
        for (int j = 0; j < 4; j++) {
            int col = bcol + wc * 64 + j * 16 + (lane & 15);
            int within = col & 1023;
            int h = within >> 6, d = within & 63;
            int rowb = brow + wr * 64 + i * 16 + (lane >> 4) * 4;
            if (part == 2) {
                // V^T: n consecutive over r -> pack 4
                int b = rowb >> 11, n = rowb & 2047;
                int bh = (b << 4) + h;
                short4v pv;
#pragma unroll
                for (int r = 0; r < 4; r++) pv[r] = (short)f2bf(acc[i][j][r]);
                *(short4v*)(Vt + ((size_t)bh * 64 + d) * 2048 + n) = pv;
            } else {
#pragma unroll
                for (int r = 0; r < 4; r++) {
                    int row = rowb + r;
                    int b = row >> 11, n = row & 2047;
                    int bh = (b << 4) + h;
                    float val = acc[i][j][r];
                    if (part == 0)
                        Qb[((size_t)bh * 2048 + n) * 64 + d] = f2bf(val * QSCALE_LOG2E);
                    else
                        Kb[((size_t)bh * 2048 + n) * 64 + d] = f2bf(val);
                }
            }
        }
    }
}

// out GEMM: att[8192][1024] @ w_out + b_out -> f32 out
__global__ __launch_bounds__(256) void gemm_out(
    const unsigned short* __restrict__ A, const unsigned short* __restrict__ Bt,
    const float* __restrict__ bias, float* __restrict__ out) {
    __shared__ __align__(16) short As[128 * 32];
    __shared__ __align__(16) short Bs[128 * 32];
    int brow = blockIdx.y * 128, bcol = blockIdx.x * 128;
    f32x4 acc[4][4] = {};
    gemm_core(A, Bt, DIM, brow, bcol, As, Bs, acc);

    int t = threadIdx.x, w = t >> 6, lane = t & 63;
    int wr = w >> 1, wc = w & 1;
#pragma unroll
    for (int i = 0; i < 4; i++) {
#pragma unroll
        for (int j = 0; j < 4; j++) {
            int col = bcol + wc * 64 + j * 16 + (lane & 15);
            float bv = bias[col];
#pragma unroll
            for (int r = 0; r < 4; r++) {
                int row = brow + wr * 64 + i * 16 + (lane >> 4) * 4 + r;
                out[(size_t)row * DIM + col] = acc[i][j][r] + bv;
            }
        }
    }
}

// ---------------- flash attention (LDS-staged, double-buffered, prefetched) ----------------
// grid (NSEQ/64, 64): x = q-tile, y = b*16+h. 4 waves * 16 q-rows each. KV tile 64.
// K-tile and V-tile staged via global_load_lds with pre-swizzled global source
// (XOR swizzle byte ^= (row&7)<<4) so stride-128B ds_read_b128 frag reads are
// conflict-spread. One vmcnt(0)+barrier per KV-tile (2-phase pipeline).
#define LOG2E_THR 11.5f  // defer-max threshold: 8 * log2(e)

__global__ __launch_bounds__(256) void attn_kernel(
    const unsigned short* __restrict__ Qb, const unsigned short* __restrict__ Kb,
    const unsigned short* __restrict__ Vt, const float* __restrict__ pos,
    unsigned short* __restrict__ att) {
    __shared__ __align__(16) char Ks[2][8192];
    __shared__ __align__(16) char Vs[2][8192];
    __shared__ __align__(16) char Plds[4 * 2048];
    int t = threadIdx.x, w = t >> 6, lane = t & 63;
    int q16 = lane & 15, g = lane >> 4;
    int bh = blockIdx.y;
    int b = bh >> 4, h = bh & 15;
    int qrow = blockIdx.x * 64 + w * 16 + q16;  // this lane's q row

    const unsigned short* Qh = Qb + (size_t)bh * NSEQ * DH;
    const char* Khc = (const char*)(Kb + (size_t)bh * NSEQ * DH);
    const char* Vhc = (const char*)(Vt + (size_t)bh * DH * NSEQ);

    bf16x8 qf[2];
#pragma unroll
    for (int ks = 0; ks < 2; ks++)
        qf[ks] = *(const bf16x8*)(Qh + (size_t)qrow * DH + ks * 32 + g * 8);

    f32x4 accT[4] = {};
    float mrun = -INFINITY, lsum = 0.f;
    char* Pw = Plds + w * 2048 + q16 * 128;
    int swz = (q16 & 7) << 4;

    // cooperative stage of one 64-kv tile of K and V^T into LDS buffer `buf`
    auto stage = [&](int buf, int kv0) {
#pragma unroll
        for (int i = 0; i < 2; i++) {
            int base = (i * 4 + w) * 1024;      // wave-uniform LDS chunk
            int o = base + lane * 16;           // this lane's (implicit) dest byte
            int row = o >> 7;                   // tile row (kv for K, d for V)
            int colb = (o & 127) ^ ((row & 7) << 4);  // pre-swizzled source col
            glds16(Khc + ((size_t)(kv0 + row) << 7) + colb, Ks[buf] + base);
            glds16(Vhc + ((size_t)row << 12) + ((size_t)kv0 << 1) + colb, Vs[buf] + base);
        }
    };

    stage(0, 0);
    asm volatile("s_waitcnt vmcnt(0)");
    __syncthreads();
    int cur = 0;

    for (int kv0 = 0; kv0 < NSEQ; kv0 += 64) {
        if (kv0 + 64 < NSEQ) stage(cur ^ 1, kv0 + 64);  // prefetch next tile

        const char* Kc = Ks[cur];
        const char* Vc = Vs[cur];

        // S^T tile: st[mf] holds kv rows (kv0 + mf*16 + g*4 + r), col = q16
        f32x4 st[4];
#pragma unroll
        for (int mf = 0; mf < 4; mf++) {
            int row = mf * 16 + q16;
            int sw = (row & 7) << 4;
            f32x4 s = {0.f, 0.f, 0.f, 0.f};
#pragma unroll
            for (int ks = 0; ks < 2; ks++) {
                bf16x8 kf = *(const bf16x8*)(Kc + row * 128 + ((ks * 64 + g * 16) ^ sw));
                s = __builtin_amdgcn_mfma_f32_16x16x32_bf16(kf, qf[ks], s, 0, 0, 0);
            }
            st[mf] = s;
        }
        // online softmax (log2 domain; scale folded into Q), defer-max (T13)
        float pm = st[0][0];
#pragma unroll
        for (int mf = 0; mf < 4; mf++)
#pragma unroll
            for (int r = 0; r < 4; r++) pm = fmaxf(pm, st[mf][r]);
        pm = fmaxf(pm, __shfl_xor(pm, 16));
        pm = fmaxf(pm, __shfl_xor(pm, 32));
        if (!__all(pm - mrun <= LOG2E_THR)) {
            float mnew = fmaxf(mrun, pm);
            float scale = exp2f(mrun - mnew);
            lsum *= scale;
#pragma unroll
            for (int mf = 0; mf < 4; mf++) accT[mf] *= scale;
            mrun = mnew;
        }
        float p[4][4];
        float rsum = 0.f;
#pragma unroll
        for (int mf = 0; mf < 4; mf++)
#pragma unroll
            for (int r = 0; r < 4; r++) {
                float e = exp2f(st[mf][r] - mrun);
                p[mf][r] = e;
                rsum += e;
            }
        rsum += __shfl_xor(rsum, 16);
        rsum += __shfl_xor(rsum, 32);
        lsum += rsum;

        // P -> LDS (bf16, XOR-swizzled), layout [q16][kv]
#pragma unroll
        for (int f = 0; f < 4; f++) {
            short4v pv;
#pragma unroll
            for (int r = 0; r < 4; r++) pv[r] = (short)f2bf(p[f][r]);
            *(short4v*)(Pw + ((f * 32 + g * 8) ^ swz)) = pv;
        }
        // PV: accT[mf] (d rows) += V^T * P^T
#pragma unroll
        for (int ks = 0; ks < 2; ks++) {
            bf16x8 pb = *(const bf16x8*)(Pw + ((ks * 64 + g * 16) ^ swz));
#pragma unroll
            for (int mf = 0; mf < 4; mf++) {
                int row = mf * 16 + q16;
                bf16x8 vf = *(const bf16x8*)(Vc + row * 128 + ((ks * 64 + g * 16) ^ ((row & 7) << 4)));
                accT[mf] = __builtin_amdgcn_mfma_f32_16x16x32_bf16(vf, pb, accT[mf], 0, 0, 0);
            }
        }

        asm volatile("s_waitcnt vmcnt(0)");  // prefetch landed
        __syncthreads();
        cur ^= 1;
    }

    // epilogue: out[q][d] = accT[d][q]/lsum + pos ; store bf16
    float inv = 1.0f / lsum;
    size_t rowbase = ((size_t)b * NSEQ + qrow) * DIM + h * 64;
#pragma unroll
    for (int mf = 0; mf < 4; mf++) {
        int dbase = mf * 16 + g * 4;
        float4 pv4 = *(const float4*)(pos + rowbase + dbase);
        short4v o;
        o[0] = (short)f2bf(accT[mf][0] * inv + pv4.x);
        o[1] = (short)f2bf(accT[mf][1] * inv + pv4.y);
        o[2] = (short)f2bf(accT[mf][2] * inv + pv4.z);
        o[3] = (short)f2bf(accT[mf][3] * inv + pv4.w);
        *(short4v*)(att + rowbase + dbase) = o;
    }
}

extern "C" void kernel_launch(void* const* d_in, const int* in_sizes, int n_in,
                              void* d_out, int out_size, void* d_ws, size_t ws_size,
                              hipStream_t stream) {
    const float* x = (const float*)d_in[0];
    const float* pos = (const float*)d_in[1];
    const float* w_qkv = (const float*)d_in[2];
    const float* w_out = (const float*)d_in[3];
    const float* b_out = (const float*)d_in[4];
    const float* ln_g = (const float*)d_in[5];
    const float* ln_b = (const float*)d_in[6];
    float* out = (float*)d_out;

    char* ws = (char*)d_ws;
    unsigned short* xn      = (unsigned short*)(ws);                       // 16MB (reused as att)
    unsigned short* wqkv_bt = (unsigned short*)(ws + (16ull << 20));       // 6MB
    unsigned short* wout_bt = (unsigned short*)(ws + (22ull << 20));       // 2MB
    unsigned short* Qb      = (unsigned short*)(ws + (24ull << 20));       // 16MB
    unsigned short* Kb      = (unsigned short*)(ws + (40ull << 20));       // 16MB
    unsigned short* Vt      = (unsigned short*)(ws + (56ull << 20));       // 16MB
    unsigned short* att     = xn;                                          // reuse

    transpose_to_bf16<<<dim3(N3 / 64, DIM / 64), 256, 0, stream>>>(w_qkv, wqkv_bt, DIM, N3);
    transpose_to_bf16<<<dim3(DIM / 64, DIM / 64), 256, 0, stream>>>(w_out, wout_bt, DIM, DIM);
    ln_kernel<<<TOKENS, 256, 0, stream>>>(x, ln_g, ln_b, xn);
    gemm_qkv<<<dim3(N3 / 128, TOKENS / 128), 256, 0, stream>>>(xn, wqkv_bt, Qb, Kb, Vt);
    attn_kernel<<<dim3(NSEQ / 64, 64), 256, 0, stream>>>(Qb, Kb, Vt, pos, att);
    gemm_out<<<dim3(DIM / 128, TOKENS / 128), 256, 0, stream>>>(att, wout_bt, b_out, out);
}